// Round 7
// baseline (873.644 us; speedup 1.0000x reference)
//
#include <hip/hip_runtime.h>
#include <hip/hip_bf16.h>

#define N_NODES 50000
#define N_EDGES 800000
#define EMB 64
#define HID 64
#define N_CLASSES 10
#define N_GRAPHS 512

#define BKT_SHIFT 6
#define BKT_NODES 64
#define NB_BKT ((N_NODES + BKT_NODES - 1) / BKT_NODES)   // 782
#define ACC_STRIDE 65                                    // bank-spread padding
#define EB_CHUNK 4096
#define EB_BLOCKS ((N_EDGES + EB_CHUNK - 1) / EB_CHUNK)  // 196

// ---------------- CSR-lite build: bucket multi-split only ----------------

__global__ __launch_bounds__(256) void k_bhist(const int* __restrict__ edst,
                                               int* __restrict__ bhist) {
    __shared__ int h[NB_BKT];
    for (int i = threadIdx.x; i < NB_BKT; i += 256) h[i] = 0;
    __syncthreads();
    int base = blockIdx.x * EB_CHUNK;
    int end = min(base + EB_CHUNK, N_EDGES);
    for (int i = base + threadIdx.x; i < end; i += 256)
        atomicAdd(&h[edst[i] >> BKT_SHIFT], 1);
    __syncthreads();
    for (int i = threadIdx.x; i < NB_BKT; i += 256)
        if (h[i]) atomicAdd(&bhist[i], h[i]);
}

__global__ void k_bscan(const int* __restrict__ bhist,
                        int* __restrict__ bucket_start,
                        int* __restrict__ bucket_cursor) {
    __shared__ int tmp[1024];
    int tid = threadIdx.x;
    int v = (tid < NB_BKT) ? bhist[tid] : 0;
    tmp[tid] = v;
    __syncthreads();
    for (int off = 1; off < 1024; off <<= 1) {
        int t = (tid >= off) ? tmp[tid - off] : 0;
        __syncthreads();
        tmp[tid] += t;
        __syncthreads();
    }
    if (tid < NB_BKT) {
        int s = tmp[tid] - v;
        bucket_start[tid] = s;
        bucket_cursor[tid] = s;
    }
    if (tid == 0) bucket_start[NB_BKT] = N_EDGES;
}

// multi-split: ebuf entries packed (local_dst<<16)|src, grouped by bucket.
__global__ __launch_bounds__(256) void k_bsplit(const int* __restrict__ esrc,
                                                const int* __restrict__ edst,
                                                int* __restrict__ bucket_cursor,
                                                int* __restrict__ ebuf) {
    __shared__ int h[NB_BKT];
    __shared__ int bbase[NB_BKT];
    __shared__ int cur[NB_BKT];
    for (int i = threadIdx.x; i < NB_BKT; i += 256) { h[i] = 0; cur[i] = 0; }
    __syncthreads();
    int base = blockIdx.x * EB_CHUNK;
    int end = min(base + EB_CHUNK, N_EDGES);
    for (int i = base + threadIdx.x; i < end; i += 256)
        atomicAdd(&h[edst[i] >> BKT_SHIFT], 1);
    __syncthreads();
    for (int i = threadIdx.x; i < NB_BKT; i += 256)
        if (h[i]) bbase[i] = atomicAdd(&bucket_cursor[i], h[i]);
    __syncthreads();
    for (int i = base + threadIdx.x; i < end; i += 256) {
        int d = edst[i], s = esrc[i];
        int b = d >> BKT_SHIFT;
        int r = atomicAdd(&cur[b], 1);
        ebuf[bbase[b] + r] = ((d & (BKT_NODES - 1)) << 16) | s;
    }
}

// ---------------- dense transform: P(bf16) = X@Wl ; Q(->H,f32) = X@Wr + bl ----------------
#define XPAD 68
__global__ __launch_bounds__(256) void k_xform(
    const int* __restrict__ ids, const float* __restrict__ src,
    const float* __restrict__ Wl, const float* __restrict__ bl,
    const float* __restrict__ Wr,
    __hip_bfloat16* __restrict__ Pb, float* __restrict__ Qout) {
    __shared__ float sWl[64 * 64];
    __shared__ float sWr[64 * 64];
    __shared__ float sX[64 * XPAD];
    int t = threadIdx.x;
    int tile = blockIdx.x * 64;
    for (int i = t; i < 64 * 16; i += 256) {
        ((float4*)sWl)[i] = ((const float4*)Wl)[i];
        ((float4*)sWr)[i] = ((const float4*)Wr)[i];
    }
    for (int i = t; i < 64 * 16; i += 256) {
        int r = i >> 4, c = i & 15;
        int node = tile + r;
        float4 v = make_float4(0.f, 0.f, 0.f, 0.f);
        if (node < N_NODES) {
            const float* srow = ids ? (src + (size_t)ids[node] * 64)
                                    : (src + (size_t)node * 64);
            v = ((const float4*)srow)[c];
        }
        *(float4*)&sX[r * XPAD + c * 4] = v;
    }
    __syncthreads();
    int dg = t & 15;
    int ng = t >> 4;
    float accL[4][4], accR[4][4];
#pragma unroll
    for (int i = 0; i < 4; i++)
#pragma unroll
        for (int j = 0; j < 4; j++) { accL[i][j] = 0.f; accR[i][j] = 0.f; }
#pragma unroll 4
    for (int k = 0; k < 64; k++) {
        float4 wl = *(const float4*)&sWl[k * 64 + dg * 4];
        float4 wr = *(const float4*)&sWr[k * 64 + dg * 4];
#pragma unroll
        for (int i = 0; i < 4; i++) {
            float xv = sX[(ng + i * 16) * XPAD + k];
            accL[i][0] = fmaf(xv, wl.x, accL[i][0]);
            accL[i][1] = fmaf(xv, wl.y, accL[i][1]);
            accL[i][2] = fmaf(xv, wl.z, accL[i][2]);
            accL[i][3] = fmaf(xv, wl.w, accL[i][3]);
            accR[i][0] = fmaf(xv, wr.x, accR[i][0]);
            accR[i][1] = fmaf(xv, wr.y, accR[i][1]);
            accR[i][2] = fmaf(xv, wr.z, accR[i][2]);
            accR[i][3] = fmaf(xv, wr.w, accR[i][3]);
        }
    }
    float4 blv = *(const float4*)&bl[dg * 4];
#pragma unroll
    for (int i = 0; i < 4; i++) {
        int node = tile + ng + i * 16;
        if (node < N_NODES) {
            union { ushort4 u; __hip_bfloat16 h[4]; } pk;
            pk.h[0] = __float2bfloat16(accL[i][0]);
            pk.h[1] = __float2bfloat16(accL[i][1]);
            pk.h[2] = __float2bfloat16(accL[i][2]);
            pk.h[3] = __float2bfloat16(accL[i][3]);
            *(ushort4*)&Pb[(size_t)node * 64 + dg * 4] = pk.u;
            *(float4*)&Qout[(size_t)node * 64 + dg * 4] =
                make_float4(accR[i][0] + blv.x, accR[i][1] + blv.y,
                            accR[i][2] + blv.z, accR[i][3] + blv.w);
        }
    }
}

// ---------------- aggregate: edge-parallel, LDS accumulation per bucket ----------------
// One block per bucket (64 dst nodes). Quarter-wave group g handles one edge:
// 16 lanes x uint2 (4 bf16 dims each) = 128B row; ds_add_f32 into acc[ldst][*].
// H[i] = relu(acc[i]/deg + H[i]) in epilogue. Block owns its 64 rows of H.
__global__ __launch_bounds__(256) void k_agg(
    const int* __restrict__ bucket_start, const int* __restrict__ ebuf,
    const __hip_bfloat16* __restrict__ Pb, float* __restrict__ H) {
    __shared__ float acc[BKT_NODES * ACC_STRIDE];
    __shared__ int ldeg[BKT_NODES];
    int b = blockIdx.x, tid = threadIdx.x;
    int bs = bucket_start[b], be = bucket_start[b + 1];
    for (int i = tid; i < BKT_NODES * ACC_STRIDE; i += 256) acc[i] = 0.f;
    if (tid < BKT_NODES) ldeg[tid] = 0;
    __syncthreads();
    int w = tid >> 6, lane = tid & 63;
    int g = lane >> 4;      // edge slot within 4-edge group
    int sl = lane & 15;     // 4-dim slot within the row
    // wave w: 16 edges per iteration (4 groups x 4 edges), block stride 64
    for (int e0 = bs + w * 16; e0 < be; e0 += 64) {
        int p[4]; bool has[4];
#pragma unroll
        for (int u = 0; u < 4; u++) {
            int e = e0 + u * 4 + g;
            has[u] = e < be;
            p[u] = has[u] ? ebuf[e] : 0;
        }
        uint2 v[4];
#pragma unroll
        for (int u = 0; u < 4; u++) {
            int s = p[u] & 0xFFFF;
            v[u] = has[u] ? *(const uint2*)(Pb + (size_t)s * 64 + sl * 4)
                          : make_uint2(0u, 0u);
        }
#pragma unroll
        for (int u = 0; u < 4; u++) {
            if (has[u]) {
                int d = p[u] >> 16;
                int base = d * ACC_STRIDE + sl * 4;
                atomicAdd(&acc[base + 0], __uint_as_float(v[u].x << 16));
                atomicAdd(&acc[base + 1], __uint_as_float(v[u].x & 0xFFFF0000u));
                atomicAdd(&acc[base + 2], __uint_as_float(v[u].y << 16));
                atomicAdd(&acc[base + 3], __uint_as_float(v[u].y & 0xFFFF0000u));
                if (sl == 0) atomicAdd(&ldeg[d], 1);
            }
        }
    }
    __syncthreads();
    int nb = b * BKT_NODES;
    for (int i = tid; i < BKT_NODES * HID; i += 256) {
        int ln = i >> 6, d = i & 63;
        int node = nb + ln;
        if (node < N_NODES) {
            int deg = ldeg[ln];
            float inv = (deg > 0) ? 1.0f / (float)deg : 0.0f;
            size_t off = (size_t)node * 64 + d;
            H[off] = fmaxf(fmaf(acc[ln * ACC_STRIDE + d], inv, H[off]), 0.0f);
        }
    }
}

// ---------------- pool + output (binary search on sorted batch) ----------------
__device__ __forceinline__ int lower_bound_batch(const int* __restrict__ batch, int val) {
    int lo = 0, hi = N_NODES;
    while (lo < hi) {
        int mid = (lo + hi) >> 1;
        if (batch[mid] < val) lo = mid + 1; else hi = mid;
    }
    return lo;
}

__global__ __launch_bounds__(256) void k_pool_out(
    const int* __restrict__ batch, const float* __restrict__ H,
    const float* __restrict__ Wout, const float* __restrict__ bout,
    float* __restrict__ out) {
    __shared__ float part[4][64];
    int g = blockIdx.x;
    int w = threadIdx.x >> 6, lane = threadIdx.x & 63;
    int s0 = lower_bound_batch(batch, g);
    int s1 = lower_bound_batch(batch, g + 1);
    float p0 = 0.f, p1 = 0.f;
    for (int n = s0 + w; n < s1; n += 8) {
        p0 += H[(size_t)n * 64 + lane];
        int n2 = n + 4;
        if (n2 < s1) p1 += H[(size_t)n2 * 64 + lane];
    }
    part[w][lane] = p0 + p1;
    __syncthreads();
    if (w == 0) {
        int cnt = s1 - s0;
        float inv = (cnt > 0) ? 1.0f / (float)cnt : 0.0f;
        float pooled = (part[0][lane] + part[1][lane] + part[2][lane] + part[3][lane]) * inv;
#pragma unroll
        for (int c = 0; c < N_CLASSES; c++) {
            float v = pooled * Wout[lane * N_CLASSES + c];
#pragma unroll
            for (int off = 32; off > 0; off >>= 1) v += __shfl_down(v, off, 64);
            if (lane == 0) out[(size_t)g * N_CLASSES + c] = v + bout[c];
        }
    }
}

// ---------------- launch ----------------

extern "C" void kernel_launch(void* const* d_in, const int* in_sizes, int n_in,
                              void* d_out, int out_size, void* d_ws, size_t ws_size,
                              hipStream_t stream) {
    const int*   node_ids = (const int*)d_in[0];
    const int*   edge_idx = (const int*)d_in[1];   // [2, E] row-major
    const int*   batch    = (const int*)d_in[2];
    const float* emb      = (const float*)d_in[3];
    const float* Wl0      = (const float*)d_in[4];
    const float* bl0      = (const float*)d_in[5];
    const float* Wr0      = (const float*)d_in[6];
    const float* Wl1      = (const float*)d_in[7];
    const float* bl1      = (const float*)d_in[8];
    const float* Wr1      = (const float*)d_in[9];
    const float* Wout     = (const float*)d_in[10];
    const float* bout     = (const float*)d_in[11];
    float* out = (float*)d_out;

    const int* esrc = edge_idx;
    const int* edst = edge_idx + N_EDGES;

    // workspace layout
    __hip_bfloat16* Pb = (__hip_bfloat16*)d_ws;            // N*64 bf16 (6.4 MB)
    float* H = (float*)(Pb + (size_t)N_NODES * 64);        // N*64 f32 (12.8 MB)
    int* ebuf          = (int*)(H + (size_t)N_NODES * 64); // E ints (3.2 MB)
    int* bhist         = ebuf + N_EDGES;                   // NB
    int* bucket_start  = bhist + NB_BKT;                   // NB+1
    int* bucket_cursor = bucket_start + NB_BKT + 1;        // NB

    const int BLK = 256;

    hipMemsetAsync(bhist, 0, NB_BKT * sizeof(int), stream);

    // bucket sort of edges (reused by both layers)
    k_bhist<<<EB_BLOCKS, BLK, 0, stream>>>(edst, bhist);
    k_bscan<<<1, 1024, 0, stream>>>(bhist, bucket_start, bucket_cursor);
    k_bsplit<<<EB_BLOCKS, BLK, 0, stream>>>(esrc, edst, bucket_cursor, ebuf);

    const int XFORM_BLOCKS = (N_NODES + 63) / 64;

    // layer 0 (embedding gather fused into xform staging)
    k_xform<<<XFORM_BLOCKS, BLK, 0, stream>>>(node_ids, emb, Wl0, bl0, Wr0, Pb, H);
    k_agg<<<NB_BKT, BLK, 0, stream>>>(bucket_start, ebuf, Pb, H);

    // layer 1
    k_xform<<<XFORM_BLOCKS, BLK, 0, stream>>>(nullptr, H, Wl1, bl1, Wr1, Pb, H);
    k_agg<<<NB_BKT, BLK, 0, stream>>>(bucket_start, ebuf, Pb, H);

    // pool + output (binary search replaces gstart kernel)
    k_pool_out<<<N_GRAPHS, BLK, 0, stream>>>(batch, H, Wout, bout, out);
}

// Round 8
// 238.298 us; speedup vs baseline: 3.6662x; 3.6662x over previous
//
#include <hip/hip_runtime.h>
#include <hip/hip_bf16.h>

#define N_NODES 50000
#define N_EDGES 800000
#define EMB 64
#define HID 64
#define N_CLASSES 10
#define N_GRAPHS 512

#define BKT_SHIFT 7
#define BKT_NODES 128
#define NB_BKT ((N_NODES + BKT_NODES - 1) / BKT_NODES)   // 391
#define EB_CHUNK 8192
#define EB_BLOCKS ((N_EDGES + EB_CHUNK - 1) / EB_CHUNK)  // 98
#define XFORM_BLOCKS ((N_NODES + 63) / 64)               // 782
#define XPAD 68

// bf16 row accumulate: 8 bf16 dims (uint4) into fp32[8]
#define ACC8(vv, A)                                                            \
    do {                                                                       \
        A[0] += __uint_as_float((vv).x << 16);                                 \
        A[1] += __uint_as_float((vv).x & 0xFFFF0000u);                         \
        A[2] += __uint_as_float((vv).y << 16);                                 \
        A[3] += __uint_as_float((vv).y & 0xFFFF0000u);                         \
        A[4] += __uint_as_float((vv).z << 16);                                 \
        A[5] += __uint_as_float((vv).z & 0xFFFF0000u);                         \
        A[6] += __uint_as_float((vv).w << 16);                                 \
        A[7] += __uint_as_float((vv).w & 0xFFFF0000u);                         \
    } while (0)

// mean over neighbors of `node` for lane slot sl (8 dims), register reduction.
__device__ __forceinline__ void agg_node8(
    int node, int sl, int sub8,
    const int* __restrict__ row_start,
    const unsigned short* __restrict__ csr_src,
    const __hip_bfloat16* __restrict__ Pb,
    float out[8]) {
    float a[4][8];
#pragma unroll
    for (int i = 0; i < 4; i++)
#pragma unroll
        for (int j = 0; j < 8; j++) a[i][j] = 0.f;
    int s0 = 0, s1 = 0;
    if (node < N_NODES) { s0 = row_start[node]; s1 = row_start[node + 1]; }
    for (int base = s0; base < s1; base += 8) {
        int cnt = min(8, s1 - base);
        int idxv = 0;
        if (base + sl < s1) idxv = csr_src[base + sl];
        if (cnt == 8) {
            int n0 = __shfl(idxv, sub8 + 0, 64);
            int n1 = __shfl(idxv, sub8 + 1, 64);
            int n2 = __shfl(idxv, sub8 + 2, 64);
            int n3 = __shfl(idxv, sub8 + 3, 64);
            int n4 = __shfl(idxv, sub8 + 4, 64);
            int n5 = __shfl(idxv, sub8 + 5, 64);
            int n6 = __shfl(idxv, sub8 + 6, 64);
            int n7 = __shfl(idxv, sub8 + 7, 64);
            uint4 v0 = ((const uint4*)(Pb + (size_t)n0 * 64))[sl];
            uint4 v1 = ((const uint4*)(Pb + (size_t)n1 * 64))[sl];
            uint4 v2 = ((const uint4*)(Pb + (size_t)n2 * 64))[sl];
            uint4 v3 = ((const uint4*)(Pb + (size_t)n3 * 64))[sl];
            uint4 v4 = ((const uint4*)(Pb + (size_t)n4 * 64))[sl];
            uint4 v5 = ((const uint4*)(Pb + (size_t)n5 * 64))[sl];
            uint4 v6 = ((const uint4*)(Pb + (size_t)n6 * 64))[sl];
            uint4 v7 = ((const uint4*)(Pb + (size_t)n7 * 64))[sl];
            ACC8(v0, a[0]); ACC8(v1, a[1]); ACC8(v2, a[2]); ACC8(v3, a[3]);
            ACC8(v4, a[0]); ACC8(v5, a[1]); ACC8(v6, a[2]); ACC8(v7, a[3]);
        } else {
            for (int j = 0; j < cnt; j++) {
                int n = __shfl(idxv, sub8 + j, 64);
                uint4 v = ((const uint4*)(Pb + (size_t)n * 64))[sl];
                ACC8(v, a[j & 3]);
            }
        }
    }
    float inv = (s1 > s0) ? 1.0f / (float)(s1 - s0) : 0.0f;
#pragma unroll
    for (int j = 0; j < 8; j++)
        out[j] = (a[0][j] + a[1][j] + a[2][j] + a[3][j]) * inv;
}

// ---------------- CSR build ----------------

__global__ void k_bscan(const int* __restrict__ bhist,
                        int* __restrict__ bucket_start,
                        int* __restrict__ bucket_cursor) {
    __shared__ int tmp[512];
    int tid = threadIdx.x;
    int v = (tid < NB_BKT) ? bhist[tid] : 0;
    tmp[tid] = v;
    __syncthreads();
    for (int off = 1; off < 512; off <<= 1) {
        int t = (tid >= off) ? tmp[tid - off] : 0;
        __syncthreads();
        tmp[tid] += t;
        __syncthreads();
    }
    if (tid < NB_BKT) {
        int s = tmp[tid] - v;
        bucket_start[tid] = s;
        bucket_cursor[tid] = s;
    }
    if (tid == 0) bucket_start[NB_BKT] = N_EDGES;
}

__global__ __launch_bounds__(256) void k_bsplit(const int* __restrict__ esrc,
                                                const int* __restrict__ edst,
                                                int* __restrict__ bucket_cursor,
                                                int* __restrict__ ebuf) {
    __shared__ int h[NB_BKT];
    __shared__ int bbase[NB_BKT];
    __shared__ int cur[NB_BKT];
    for (int i = threadIdx.x; i < NB_BKT; i += 256) { h[i] = 0; cur[i] = 0; }
    __syncthreads();
    int base = blockIdx.x * EB_CHUNK;
    int end = min(base + EB_CHUNK, N_EDGES);
    for (int i = base + threadIdx.x; i < end; i += 256)
        atomicAdd(&h[edst[i] >> BKT_SHIFT], 1);
    __syncthreads();
    for (int i = threadIdx.x; i < NB_BKT; i += 256)
        if (h[i]) bbase[i] = atomicAdd(&bucket_cursor[i], h[i]);
    __syncthreads();
    for (int i = base + threadIdx.x; i < end; i += 256) {
        int d = edst[i], s = esrc[i];
        int b = d >> BKT_SHIFT;
        int r = atomicAdd(&cur[b], 1);
        ebuf[bbase[b] + r] = ((d & (BKT_NODES - 1)) << 16) | s;
    }
}

__global__ __launch_bounds__(256) void k_csr_fill(const int* __restrict__ bucket_start,
                                                  const int* __restrict__ ebuf,
                                                  int* __restrict__ row_start,
                                                  unsigned short* __restrict__ csr_src) {
    __shared__ int nhist[BKT_NODES];
    __shared__ int sval[BKT_NODES];
    __shared__ int sexcl[BKT_NODES];
    __shared__ int ncur[BKT_NODES];
    int b = blockIdx.x, tid = threadIdx.x;
    int bs = bucket_start[b], be = bucket_start[b + 1];
    if (tid < BKT_NODES) { nhist[tid] = 0; ncur[tid] = 0; }
    __syncthreads();
    for (int i = bs + tid; i < be; i += 256)
        atomicAdd(&nhist[ebuf[i] >> 16], 1);
    __syncthreads();
    if (tid < BKT_NODES) sval[tid] = nhist[tid];
    __syncthreads();
    for (int off = 1; off < BKT_NODES; off <<= 1) {
        int t = 0;
        if (tid < BKT_NODES && tid >= off) t = nhist[tid - off];
        __syncthreads();
        if (tid < BKT_NODES) nhist[tid] += t;
        __syncthreads();
    }
    if (tid < BKT_NODES) {
        sexcl[tid] = nhist[tid] - sval[tid];
        int node = b * BKT_NODES + tid;
        if (node < N_NODES) row_start[node] = bs + sexcl[tid];
    }
    if (b == 0 && tid == 0) row_start[N_NODES] = N_EDGES;
    __syncthreads();
    for (int i = bs + tid; i < be; i += 256) {
        int p = ebuf[i];
        int l = p >> 16, s = p & 0xFFFF;
        int r = atomicAdd(&ncur[l], 1);
        csr_src[bs + sexcl[l] + r] = (unsigned short)s;
    }
}

// ---------------- combo: bucket histogram (blocks 0..EB) + layer-0 xform ----------------
__global__ __launch_bounds__(256) void k_combo(
    const int* __restrict__ edst, int* __restrict__ bhist,
    const int* __restrict__ ids, const float* __restrict__ emb,
    const float* __restrict__ Wl, const float* __restrict__ bl,
    const float* __restrict__ Wr,
    __hip_bfloat16* __restrict__ Pb, float* __restrict__ Qout) {
    __shared__ float sWl[64 * 64];
    __shared__ float sWr[64 * 64];
    __shared__ float sX[64 * XPAD];
    int t = threadIdx.x;
    if (blockIdx.x < EB_BLOCKS) {
        // histogram part (reuses sWl as int scratch)
        int* h = (int*)sWl;
        for (int i = t; i < NB_BKT; i += 256) h[i] = 0;
        __syncthreads();
        int base = blockIdx.x * EB_CHUNK;
        int end = min(base + EB_CHUNK, N_EDGES);
        for (int i = base + t; i < end; i += 256)
            atomicAdd(&h[edst[i] >> BKT_SHIFT], 1);
        __syncthreads();
        for (int i = t; i < NB_BKT; i += 256)
            if (h[i]) atomicAdd(&bhist[i], h[i]);
        return;
    }
    int tile = (blockIdx.x - EB_BLOCKS) * 64;
    for (int i = t; i < 64 * 16; i += 256) {
        ((float4*)sWl)[i] = ((const float4*)Wl)[i];
        ((float4*)sWr)[i] = ((const float4*)Wr)[i];
    }
    for (int i = t; i < 64 * 16; i += 256) {
        int r = i >> 4, c = i & 15;
        int node = tile + r;
        float4 v = make_float4(0.f, 0.f, 0.f, 0.f);
        if (node < N_NODES)
            v = ((const float4*)(emb + (size_t)ids[node] * 64))[c];
        *(float4*)&sX[r * XPAD + c * 4] = v;
    }
    __syncthreads();
    int dg = t & 15, ng = t >> 4;
    float accL[4][4], accR[4][4];
#pragma unroll
    for (int i = 0; i < 4; i++)
#pragma unroll
        for (int j = 0; j < 4; j++) { accL[i][j] = 0.f; accR[i][j] = 0.f; }
#pragma unroll 4
    for (int k = 0; k < 64; k++) {
        float4 wl = *(const float4*)&sWl[k * 64 + dg * 4];
        float4 wr = *(const float4*)&sWr[k * 64 + dg * 4];
#pragma unroll
        for (int i = 0; i < 4; i++) {
            float xv = sX[(ng + i * 16) * XPAD + k];
            accL[i][0] = fmaf(xv, wl.x, accL[i][0]);
            accL[i][1] = fmaf(xv, wl.y, accL[i][1]);
            accL[i][2] = fmaf(xv, wl.z, accL[i][2]);
            accL[i][3] = fmaf(xv, wl.w, accL[i][3]);
            accR[i][0] = fmaf(xv, wr.x, accR[i][0]);
            accR[i][1] = fmaf(xv, wr.y, accR[i][1]);
            accR[i][2] = fmaf(xv, wr.z, accR[i][2]);
            accR[i][3] = fmaf(xv, wr.w, accR[i][3]);
        }
    }
    float4 blv = *(const float4*)&bl[dg * 4];
#pragma unroll
    for (int i = 0; i < 4; i++) {
        int node = tile + ng + i * 16;
        if (node < N_NODES) {
            union { ushort4 u; __hip_bfloat16 h[4]; } pk;
            pk.h[0] = __float2bfloat16(accL[i][0]);
            pk.h[1] = __float2bfloat16(accL[i][1]);
            pk.h[2] = __float2bfloat16(accL[i][2]);
            pk.h[3] = __float2bfloat16(accL[i][3]);
            *(ushort4*)&Pb[(size_t)node * 64 + dg * 4] = pk.u;
            *(float4*)&Qout[(size_t)node * 64 + dg * 4] =
                make_float4(accR[i][0] + blv.x, accR[i][1] + blv.y,
                            accR[i][2] + blv.z, accR[i][3] + blv.w);
        }
    }
}

// ---------------- fused: layer-0 aggregate (to LDS) + layer-1 xform ----------------
// Per 64-node tile: H0 = relu(mean(Pb0 neighbors) + Q0) built in LDS (never
// written to global), then P1(bf16) = H0@Wl1, H := Q1 = H0@Wr1 + bl1.
__global__ __launch_bounds__(256) void k_fused1(
    const int* __restrict__ row_start, const unsigned short* __restrict__ csr_src,
    const __hip_bfloat16* __restrict__ Pb0, const float* __restrict__ Wl,
    const float* __restrict__ bl, const float* __restrict__ Wr,
    __hip_bfloat16* __restrict__ Pb1, float* __restrict__ H) {
    __shared__ float sWl[64 * 64];
    __shared__ float sWr[64 * 64];
    __shared__ float sX[64 * XPAD];
    int t = threadIdx.x;
    int tile = blockIdx.x * 64;
    for (int i = t; i < 64 * 16; i += 256) {
        ((float4*)sWl)[i] = ((const float4*)Wl)[i];
        ((float4*)sWr)[i] = ((const float4*)Wr)[i];
    }
    // phase (a): aggregate 2 nodes per eighth-wave, results -> sX
    int grp = t >> 3, sl = t & 7, sub8 = t & 56;
    for (int nn = 0; nn < 2; nn++) {
        int ln = grp * 2 + nn;
        int node = tile + ln;
        float m[8];
        agg_node8(node, sl, sub8, row_start, csr_src, Pb0, m);
        if (node < N_NODES) {
            size_t off = (size_t)node * 64 + sl * 8;
            float4 q0 = *(const float4*)&H[off];
            float4 q1 = *(const float4*)&H[off + 4];
            m[0] = fmaxf(m[0] + q0.x, 0.f);
            m[1] = fmaxf(m[1] + q0.y, 0.f);
            m[2] = fmaxf(m[2] + q0.z, 0.f);
            m[3] = fmaxf(m[3] + q0.w, 0.f);
            m[4] = fmaxf(m[4] + q1.x, 0.f);
            m[5] = fmaxf(m[5] + q1.y, 0.f);
            m[6] = fmaxf(m[6] + q1.z, 0.f);
            m[7] = fmaxf(m[7] + q1.w, 0.f);
        } else {
#pragma unroll
            for (int j = 0; j < 8; j++) m[j] = 0.f;
        }
        *(float4*)&sX[ln * XPAD + sl * 8] = make_float4(m[0], m[1], m[2], m[3]);
        *(float4*)&sX[ln * XPAD + sl * 8 + 4] = make_float4(m[4], m[5], m[6], m[7]);
    }
    __syncthreads();
    // phase (b): GEMM on sX
    int dg = t & 15, ng = t >> 4;
    float accL[4][4], accR[4][4];
#pragma unroll
    for (int i = 0; i < 4; i++)
#pragma unroll
        for (int j = 0; j < 4; j++) { accL[i][j] = 0.f; accR[i][j] = 0.f; }
#pragma unroll 4
    for (int k = 0; k < 64; k++) {
        float4 wl = *(const float4*)&sWl[k * 64 + dg * 4];
        float4 wr = *(const float4*)&sWr[k * 64 + dg * 4];
#pragma unroll
        for (int i = 0; i < 4; i++) {
            float xv = sX[(ng + i * 16) * XPAD + k];
            accL[i][0] = fmaf(xv, wl.x, accL[i][0]);
            accL[i][1] = fmaf(xv, wl.y, accL[i][1]);
            accL[i][2] = fmaf(xv, wl.z, accL[i][2]);
            accL[i][3] = fmaf(xv, wl.w, accL[i][3]);
            accR[i][0] = fmaf(xv, wr.x, accR[i][0]);
            accR[i][1] = fmaf(xv, wr.y, accR[i][1]);
            accR[i][2] = fmaf(xv, wr.z, accR[i][2]);
            accR[i][3] = fmaf(xv, wr.w, accR[i][3]);
        }
    }
    float4 blv = *(const float4*)&bl[dg * 4];
#pragma unroll
    for (int i = 0; i < 4; i++) {
        int node = tile + ng + i * 16;
        if (node < N_NODES) {
            union { ushort4 u; __hip_bfloat16 h[4]; } pk;
            pk.h[0] = __float2bfloat16(accL[i][0]);
            pk.h[1] = __float2bfloat16(accL[i][1]);
            pk.h[2] = __float2bfloat16(accL[i][2]);
            pk.h[3] = __float2bfloat16(accL[i][3]);
            *(ushort4*)&Pb1[(size_t)node * 64 + dg * 4] = pk.u;
            *(float4*)&H[(size_t)node * 64 + dg * 4] =
                make_float4(accR[i][0] + blv.x, accR[i][1] + blv.y,
                            accR[i][2] + blv.z, accR[i][3] + blv.w);
        }
    }
}

// ---------------- layer-1 aggregate: H = relu(mean(Pb1)+H) ----------------
__global__ __launch_bounds__(256) void k_agg2(
    const int* __restrict__ row_start, const unsigned short* __restrict__ csr_src,
    const __hip_bfloat16* __restrict__ Pb, float* __restrict__ H) {
    int tid = blockIdx.x * blockDim.x + threadIdx.x;
    int node = tid >> 3;
    if (node >= N_NODES) return;
    int sl = tid & 7;
    int sub8 = threadIdx.x & 56;
    float m[8];
    agg_node8(node, sl, sub8, row_start, csr_src, Pb, m);
    size_t off = (size_t)node * 64 + sl * 8;
    float4 q0 = *(const float4*)&H[off];
    float4 q1 = *(const float4*)&H[off + 4];
    float4 r0, r1;
    r0.x = fmaxf(m[0] + q0.x, 0.f);
    r0.y = fmaxf(m[1] + q0.y, 0.f);
    r0.z = fmaxf(m[2] + q0.z, 0.f);
    r0.w = fmaxf(m[3] + q0.w, 0.f);
    r1.x = fmaxf(m[4] + q1.x, 0.f);
    r1.y = fmaxf(m[5] + q1.y, 0.f);
    r1.z = fmaxf(m[6] + q1.z, 0.f);
    r1.w = fmaxf(m[7] + q1.w, 0.f);
    *(float4*)&H[off] = r0;
    *(float4*)&H[off + 4] = r1;
}

// ---------------- pool + output (binary search on sorted batch) ----------------
__device__ __forceinline__ int lower_bound_batch(const int* __restrict__ batch, int val) {
    int lo = 0, hi = N_NODES;
    while (lo < hi) {
        int mid = (lo + hi) >> 1;
        if (batch[mid] < val) lo = mid + 1; else hi = mid;
    }
    return lo;
}

__global__ __launch_bounds__(256) void k_pool_out(
    const int* __restrict__ batch, const float* __restrict__ H,
    const float* __restrict__ Wout, const float* __restrict__ bout,
    float* __restrict__ out) {
    __shared__ float part[4][64];
    int g = blockIdx.x;
    int w = threadIdx.x >> 6, lane = threadIdx.x & 63;
    int s0 = lower_bound_batch(batch, g);
    int s1 = lower_bound_batch(batch, g + 1);
    float p0 = 0.f, p1 = 0.f;
    for (int n = s0 + w; n < s1; n += 8) {
        p0 += H[(size_t)n * 64 + lane];
        int n2 = n + 4;
        if (n2 < s1) p1 += H[(size_t)n2 * 64 + lane];
    }
    part[w][lane] = p0 + p1;
    __syncthreads();
    if (w == 0) {
        int cnt = s1 - s0;
        float inv = (cnt > 0) ? 1.0f / (float)cnt : 0.0f;
        float pooled = (part[0][lane] + part[1][lane] + part[2][lane] + part[3][lane]) * inv;
#pragma unroll
        for (int c = 0; c < N_CLASSES; c++) {
            float v = pooled * Wout[lane * N_CLASSES + c];
#pragma unroll
            for (int off = 32; off > 0; off >>= 1) v += __shfl_down(v, off, 64);
            if (lane == 0) out[(size_t)g * N_CLASSES + c] = v + bout[c];
        }
    }
}

// ---------------- launch ----------------

extern "C" void kernel_launch(void* const* d_in, const int* in_sizes, int n_in,
                              void* d_out, int out_size, void* d_ws, size_t ws_size,
                              hipStream_t stream) {
    const int*   node_ids = (const int*)d_in[0];
    const int*   edge_idx = (const int*)d_in[1];   // [2, E] row-major
    const int*   batch    = (const int*)d_in[2];
    const float* emb      = (const float*)d_in[3];
    const float* Wl0      = (const float*)d_in[4];
    const float* bl0      = (const float*)d_in[5];
    const float* Wr0      = (const float*)d_in[6];
    const float* Wl1      = (const float*)d_in[7];
    const float* bl1      = (const float*)d_in[8];
    const float* Wr1      = (const float*)d_in[9];
    const float* Wout     = (const float*)d_in[10];
    const float* bout     = (const float*)d_in[11];
    float* out = (float*)d_out;

    const int* esrc = edge_idx;
    const int* edst = edge_idx + N_EDGES;

    // workspace layout
    __hip_bfloat16* Pb0 = (__hip_bfloat16*)d_ws;            // N*64 bf16
    __hip_bfloat16* Pb1 = Pb0 + (size_t)N_NODES * 64;       // N*64 bf16
    float* H = (float*)(Pb1 + (size_t)N_NODES * 64);        // N*64 f32
    int* ebuf          = (int*)(H + (size_t)N_NODES * 64);  // E ints
    int* row_start     = ebuf + N_EDGES;                    // N+1
    int* bhist         = row_start + N_NODES + 1;           // NB
    int* bucket_start  = bhist + NB_BKT;                    // NB+1
    int* bucket_cursor = bucket_start + NB_BKT + 1;         // NB
    unsigned short* csr_src = (unsigned short*)(bucket_cursor + NB_BKT); // E

    const int BLK = 256;

    hipMemsetAsync(bhist, 0, NB_BKT * sizeof(int), stream);

    // combo: bucket histogram (98 blocks) + layer-0 xform (782 blocks)
    k_combo<<<EB_BLOCKS + XFORM_BLOCKS, BLK, 0, stream>>>(
        edst, bhist, node_ids, emb, Wl0, bl0, Wr0, Pb0, H);

    k_bscan<<<1, 512, 0, stream>>>(bhist, bucket_start, bucket_cursor);
    k_bsplit<<<EB_BLOCKS, BLK, 0, stream>>>(esrc, edst, bucket_cursor, ebuf);
    k_csr_fill<<<NB_BKT, BLK, 0, stream>>>(bucket_start, ebuf, row_start, csr_src);

    // fused layer-0 aggregate + layer-1 xform
    k_fused1<<<XFORM_BLOCKS, BLK, 0, stream>>>(
        row_start, csr_src, Pb0, Wl1, bl1, Wr1, Pb1, H);

    // layer-1 aggregate
    const int AGG_BLOCKS = (N_NODES * 8 + BLK - 1) / BLK;
    k_agg2<<<AGG_BLOCKS, BLK, 0, stream>>>(row_start, csr_src, Pb1, H);

    // pool + output
    k_pool_out<<<N_GRAPHS, BLK, 0, stream>>>(batch, H, Wout, bout, out);
}

// Round 9
// 233.644 us; speedup vs baseline: 3.7392x; 1.0199x over previous
//
#include <hip/hip_runtime.h>
#include <hip/hip_bf16.h>

#define N_NODES 50000
#define N_EDGES 800000
#define EMB 64
#define HID 64
#define N_CLASSES 10
#define N_GRAPHS 512

#define BKT_SHIFT 7
#define BKT_NODES 128
#define NB_BKT ((N_NODES + BKT_NODES - 1) / BKT_NODES)   // 391
#define BKT_CAP 2560     // mean 2048 + 11 sigma; fixed-capacity bucket regions
#define EB_CHUNK 8192
#define EB_BLOCKS ((N_EDGES + EB_CHUNK - 1) / EB_CHUNK)  // 98
#define XFORM_BLOCKS ((N_NODES + 63) / 64)               // 782
#define XPAD 68
#define POOL_SPAN 33

// bf16 row accumulate: 8 bf16 dims (uint4) into fp32[8]
#define ACC8(vv, A)                                                            \
    do {                                                                       \
        A[0] += __uint_as_float((vv).x << 16);                                 \
        A[1] += __uint_as_float((vv).x & 0xFFFF0000u);                         \
        A[2] += __uint_as_float((vv).y << 16);                                 \
        A[3] += __uint_as_float((vv).y & 0xFFFF0000u);                         \
        A[4] += __uint_as_float((vv).z << 16);                                 \
        A[5] += __uint_as_float((vv).z & 0xFFFF0000u);                         \
        A[6] += __uint_as_float((vv).w << 16);                                 \
        A[7] += __uint_as_float((vv).w & 0xFFFF0000u);                         \
    } while (0)

// mean over neighbors of `node` for lane slot sl (8 dims), register reduction.
__device__ __forceinline__ void agg_node8(
    int node, int sl, int sub8,
    const unsigned int* __restrict__ rs_deg,
    const unsigned short* __restrict__ csr_src,
    const __hip_bfloat16* __restrict__ Pb,
    float out[8]) {
    float a[4][8];
#pragma unroll
    for (int i = 0; i < 4; i++)
#pragma unroll
        for (int j = 0; j < 8; j++) a[i][j] = 0.f;
    int s0 = 0, s1 = 0;
    if (node < N_NODES) {
        unsigned int e = rs_deg[node];
        s0 = (int)(e >> 12);
        s1 = s0 + (int)(e & 4095u);
    }
    for (int base = s0; base < s1; base += 8) {
        int cnt = min(8, s1 - base);
        int idxv = 0;
        if (base + sl < s1) idxv = csr_src[base + sl];
        if (cnt == 8) {
            int n0 = __shfl(idxv, sub8 + 0, 64);
            int n1 = __shfl(idxv, sub8 + 1, 64);
            int n2 = __shfl(idxv, sub8 + 2, 64);
            int n3 = __shfl(idxv, sub8 + 3, 64);
            int n4 = __shfl(idxv, sub8 + 4, 64);
            int n5 = __shfl(idxv, sub8 + 5, 64);
            int n6 = __shfl(idxv, sub8 + 6, 64);
            int n7 = __shfl(idxv, sub8 + 7, 64);
            uint4 v0 = ((const uint4*)(Pb + (size_t)n0 * 64))[sl];
            uint4 v1 = ((const uint4*)(Pb + (size_t)n1 * 64))[sl];
            uint4 v2 = ((const uint4*)(Pb + (size_t)n2 * 64))[sl];
            uint4 v3 = ((const uint4*)(Pb + (size_t)n3 * 64))[sl];
            uint4 v4 = ((const uint4*)(Pb + (size_t)n4 * 64))[sl];
            uint4 v5 = ((const uint4*)(Pb + (size_t)n5 * 64))[sl];
            uint4 v6 = ((const uint4*)(Pb + (size_t)n6 * 64))[sl];
            uint4 v7 = ((const uint4*)(Pb + (size_t)n7 * 64))[sl];
            ACC8(v0, a[0]); ACC8(v1, a[1]); ACC8(v2, a[2]); ACC8(v3, a[3]);
            ACC8(v4, a[0]); ACC8(v5, a[1]); ACC8(v6, a[2]); ACC8(v7, a[3]);
        } else {
            for (int j = 0; j < cnt; j++) {
                int n = __shfl(idxv, sub8 + j, 64);
                uint4 v = ((const uint4*)(Pb + (size_t)n * 64))[sl];
                ACC8(v, a[j & 3]);
            }
        }
    }
    float inv = (s1 > s0) ? 1.0f / (float)(s1 - s0) : 0.0f;
#pragma unroll
    for (int j = 0; j < 8; j++)
        out[j] = (a[0][j] + a[1][j] + a[2][j] + a[3][j]) * inv;
}

// ---------------- bucket sort (fixed-capacity regions; no hist/scan) ----------------
__global__ __launch_bounds__(256) void k_bsplit(const int* __restrict__ esrc,
                                                const int* __restrict__ edst,
                                                int* __restrict__ cnt,
                                                int* __restrict__ ebuf) {
    __shared__ int h[NB_BKT];
    __shared__ int bbase[NB_BKT];
    __shared__ int cur[NB_BKT];
    for (int i = threadIdx.x; i < NB_BKT; i += 256) { h[i] = 0; cur[i] = 0; }
    __syncthreads();
    int base = blockIdx.x * EB_CHUNK;
    int end = min(base + EB_CHUNK, N_EDGES);
    for (int i = base + threadIdx.x; i < end; i += 256)
        atomicAdd(&h[edst[i] >> BKT_SHIFT], 1);
    __syncthreads();
    for (int i = threadIdx.x; i < NB_BKT; i += 256)
        if (h[i]) bbase[i] = i * BKT_CAP + atomicAdd(&cnt[i], h[i]);
    __syncthreads();
    for (int i = base + threadIdx.x; i < end; i += 256) {
        int d = edst[i], s = esrc[i];
        int b = d >> BKT_SHIFT;
        int r = atomicAdd(&cur[b], 1);
        ebuf[bbase[b] + r] = ((d & (BKT_NODES - 1)) << 16) | s;
    }
}

// per-bucket: LDS node-histogram + scan -> packed rs_deg; scatter ushort csr_src.
__global__ __launch_bounds__(256) void k_csr_fill(const int* __restrict__ cnt,
                                                  const int* __restrict__ ebuf,
                                                  unsigned int* __restrict__ rs_deg,
                                                  unsigned short* __restrict__ csr_src) {
    __shared__ int nhist[BKT_NODES];
    __shared__ int sval[BKT_NODES];
    __shared__ int sexcl[BKT_NODES];
    __shared__ int ncur[BKT_NODES];
    int b = blockIdx.x, tid = threadIdx.x;
    int bs = b * BKT_CAP, be = bs + cnt[b];
    if (tid < BKT_NODES) { nhist[tid] = 0; ncur[tid] = 0; }
    __syncthreads();
    for (int i = bs + tid; i < be; i += 256)
        atomicAdd(&nhist[ebuf[i] >> 16], 1);
    __syncthreads();
    if (tid < BKT_NODES) sval[tid] = nhist[tid];
    __syncthreads();
    for (int off = 1; off < BKT_NODES; off <<= 1) {
        int t = 0;
        if (tid < BKT_NODES && tid >= off) t = nhist[tid - off];
        __syncthreads();
        if (tid < BKT_NODES) nhist[tid] += t;
        __syncthreads();
    }
    if (tid < BKT_NODES) {
        sexcl[tid] = nhist[tid] - sval[tid];
        int node = b * BKT_NODES + tid;
        if (node < N_NODES)
            rs_deg[node] = ((unsigned int)(bs + sexcl[tid]) << 12) | (unsigned int)sval[tid];
    }
    __syncthreads();
    for (int i = bs + tid; i < be; i += 256) {
        int p = ebuf[i];
        int l = p >> 16, s = p & 0xFFFF;
        int r = atomicAdd(&ncur[l], 1);
        csr_src[bs + sexcl[l] + r] = (unsigned short)s;
    }
}

// ---------------- layer-0 transform (two-pass W): Pb0 = X@Wl0 ; H = X@Wr0+bl0 ----------------
__global__ __launch_bounds__(256) void k_xform0(
    const int* __restrict__ ids, const float* __restrict__ emb,
    const float* __restrict__ Wl, const float* __restrict__ bl,
    const float* __restrict__ Wr,
    __hip_bfloat16* __restrict__ Pb, float* __restrict__ Qout) {
    __shared__ float sW[64 * 64];
    __shared__ float sX[64 * XPAD];
    int t = threadIdx.x;
    int tile = blockIdx.x * 64;
    for (int i = t; i < 64 * 16; i += 256)
        ((float4*)sW)[i] = ((const float4*)Wl)[i];
    for (int i = t; i < 64 * 16; i += 256) {
        int r = i >> 4, c = i & 15;
        int node = tile + r;
        float4 v = make_float4(0.f, 0.f, 0.f, 0.f);
        if (node < N_NODES)
            v = ((const float4*)(emb + (size_t)ids[node] * 64))[c];
        *(float4*)&sX[r * XPAD + c * 4] = v;
    }
    __syncthreads();
    int dg = t & 15, ng = t >> 4;
    float acc[4][4];
#pragma unroll
    for (int i = 0; i < 4; i++)
#pragma unroll
        for (int j = 0; j < 4; j++) acc[i][j] = 0.f;
#pragma unroll 4
    for (int k = 0; k < 64; k++) {
        float4 w = *(const float4*)&sW[k * 64 + dg * 4];
#pragma unroll
        for (int i = 0; i < 4; i++) {
            float xv = sX[(ng + i * 16) * XPAD + k];
            acc[i][0] = fmaf(xv, w.x, acc[i][0]);
            acc[i][1] = fmaf(xv, w.y, acc[i][1]);
            acc[i][2] = fmaf(xv, w.z, acc[i][2]);
            acc[i][3] = fmaf(xv, w.w, acc[i][3]);
        }
    }
#pragma unroll
    for (int i = 0; i < 4; i++) {
        int node = tile + ng + i * 16;
        if (node < N_NODES) {
            union { ushort4 u; __hip_bfloat16 h[4]; } pk;
            pk.h[0] = __float2bfloat16(acc[i][0]);
            pk.h[1] = __float2bfloat16(acc[i][1]);
            pk.h[2] = __float2bfloat16(acc[i][2]);
            pk.h[3] = __float2bfloat16(acc[i][3]);
            *(ushort4*)&Pb[(size_t)node * 64 + dg * 4] = pk.u;
        }
    }
    __syncthreads();
    for (int i = t; i < 64 * 16; i += 256)
        ((float4*)sW)[i] = ((const float4*)Wr)[i];
    __syncthreads();
#pragma unroll
    for (int i = 0; i < 4; i++)
#pragma unroll
        for (int j = 0; j < 4; j++) acc[i][j] = 0.f;
#pragma unroll 4
    for (int k = 0; k < 64; k++) {
        float4 w = *(const float4*)&sW[k * 64 + dg * 4];
#pragma unroll
        for (int i = 0; i < 4; i++) {
            float xv = sX[(ng + i * 16) * XPAD + k];
            acc[i][0] = fmaf(xv, w.x, acc[i][0]);
            acc[i][1] = fmaf(xv, w.y, acc[i][1]);
            acc[i][2] = fmaf(xv, w.z, acc[i][2]);
            acc[i][3] = fmaf(xv, w.w, acc[i][3]);
        }
    }
    float4 blv = *(const float4*)&bl[dg * 4];
#pragma unroll
    for (int i = 0; i < 4; i++) {
        int node = tile + ng + i * 16;
        if (node < N_NODES)
            *(float4*)&Qout[(size_t)node * 64 + dg * 4] =
                make_float4(acc[i][0] + blv.x, acc[i][1] + blv.y,
                            acc[i][2] + blv.z, acc[i][3] + blv.w);
    }
}

// ---------------- fused: layer-0 aggregate (to LDS) + layer-1 xform (two-pass W) ----------------
__global__ __launch_bounds__(256) void k_fused1(
    const unsigned int* __restrict__ rs_deg, const unsigned short* __restrict__ csr_src,
    const __hip_bfloat16* __restrict__ Pb0, const float* __restrict__ Wl,
    const float* __restrict__ bl, const float* __restrict__ Wr,
    __hip_bfloat16* __restrict__ Pb1, float* __restrict__ H) {
    __shared__ float sW[64 * 64];
    __shared__ float sX[64 * XPAD];
    int t = threadIdx.x;
    int tile = blockIdx.x * 64;
    // prefetch Wl into LDS; hides behind the gather phase
    for (int i = t; i < 64 * 16; i += 256)
        ((float4*)sW)[i] = ((const float4*)Wl)[i];
    // phase (a): aggregate 2 nodes per eighth-wave, H0 = relu(mean+Q0) -> sX
    int grp = t >> 3, sl = t & 7, sub8 = t & 56;
    for (int nn = 0; nn < 2; nn++) {
        int ln = grp * 2 + nn;
        int node = tile + ln;
        float m[8];
        agg_node8(node, sl, sub8, rs_deg, csr_src, Pb0, m);
        if (node < N_NODES) {
            size_t off = (size_t)node * 64 + sl * 8;
            float4 q0 = *(const float4*)&H[off];
            float4 q1 = *(const float4*)&H[off + 4];
            m[0] = fmaxf(m[0] + q0.x, 0.f);
            m[1] = fmaxf(m[1] + q0.y, 0.f);
            m[2] = fmaxf(m[2] + q0.z, 0.f);
            m[3] = fmaxf(m[3] + q0.w, 0.f);
            m[4] = fmaxf(m[4] + q1.x, 0.f);
            m[5] = fmaxf(m[5] + q1.y, 0.f);
            m[6] = fmaxf(m[6] + q1.z, 0.f);
            m[7] = fmaxf(m[7] + q1.w, 0.f);
        } else {
#pragma unroll
            for (int j = 0; j < 8; j++) m[j] = 0.f;
        }
        *(float4*)&sX[ln * XPAD + sl * 8] = make_float4(m[0], m[1], m[2], m[3]);
        *(float4*)&sX[ln * XPAD + sl * 8 + 4] = make_float4(m[4], m[5], m[6], m[7]);
    }
    __syncthreads();
    // phase (b1): Pb1 = H0 @ Wl
    int dg = t & 15, ng = t >> 4;
    float acc[4][4];
#pragma unroll
    for (int i = 0; i < 4; i++)
#pragma unroll
        for (int j = 0; j < 4; j++) acc[i][j] = 0.f;
#pragma unroll 4
    for (int k = 0; k < 64; k++) {
        float4 w = *(const float4*)&sW[k * 64 + dg * 4];
#pragma unroll
        for (int i = 0; i < 4; i++) {
            float xv = sX[(ng + i * 16) * XPAD + k];
            acc[i][0] = fmaf(xv, w.x, acc[i][0]);
            acc[i][1] = fmaf(xv, w.y, acc[i][1]);
            acc[i][2] = fmaf(xv, w.z, acc[i][2]);
            acc[i][3] = fmaf(xv, w.w, acc[i][3]);
        }
    }
#pragma unroll
    for (int i = 0; i < 4; i++) {
        int node = tile + ng + i * 16;
        if (node < N_NODES) {
            union { ushort4 u; __hip_bfloat16 h[4]; } pk;
            pk.h[0] = __float2bfloat16(acc[i][0]);
            pk.h[1] = __float2bfloat16(acc[i][1]);
            pk.h[2] = __float2bfloat16(acc[i][2]);
            pk.h[3] = __float2bfloat16(acc[i][3]);
            *(ushort4*)&Pb1[(size_t)node * 64 + dg * 4] = pk.u;
        }
    }
    __syncthreads();
    for (int i = t; i < 64 * 16; i += 256)
        ((float4*)sW)[i] = ((const float4*)Wr)[i];
    __syncthreads();
    // phase (b2): H = Q1 = H0 @ Wr + bl
#pragma unroll
    for (int i = 0; i < 4; i++)
#pragma unroll
        for (int j = 0; j < 4; j++) acc[i][j] = 0.f;
#pragma unroll 4
    for (int k = 0; k < 64; k++) {
        float4 w = *(const float4*)&sW[k * 64 + dg * 4];
#pragma unroll
        for (int i = 0; i < 4; i++) {
            float xv = sX[(ng + i * 16) * XPAD + k];
            acc[i][0] = fmaf(xv, w.x, acc[i][0]);
            acc[i][1] = fmaf(xv, w.y, acc[i][1]);
            acc[i][2] = fmaf(xv, w.z, acc[i][2]);
            acc[i][3] = fmaf(xv, w.w, acc[i][3]);
        }
    }
    float4 blv = *(const float4*)&bl[dg * 4];
#pragma unroll
    for (int i = 0; i < 4; i++) {
        int node = tile + ng + i * 16;
        if (node < N_NODES)
            *(float4*)&H[(size_t)node * 64 + dg * 4] =
                make_float4(acc[i][0] + blv.x, acc[i][1] + blv.y,
                            acc[i][2] + blv.z, acc[i][3] + blv.w);
    }
}

// ---------------- layer-1 aggregate fused with pooling ----------------
// 32 consecutive nodes per block; h = relu(mean(Pb1)+Q1) reduced per-graph in
// LDS (batch sorted -> span <= 33 barring empty graphs; fallback direct atomics).
__global__ __launch_bounds__(256) void k_agg2_pool(
    const unsigned int* __restrict__ rs_deg, const unsigned short* __restrict__ csr_src,
    const __hip_bfloat16* __restrict__ Pb, const float* __restrict__ H,
    const int* __restrict__ batch, float* __restrict__ psum) {
    __shared__ float acc[POOL_SPAN * 64];
    int t = threadIdx.x;
    for (int i = t; i < POOL_SPAN * 64; i += 256) acc[i] = 0.f;
    int nb = blockIdx.x * 32;
    int gmin = batch[nb < N_NODES ? nb : N_NODES - 1];
    __syncthreads();
    int node = nb + (t >> 3);
    int sl = t & 7, sub8 = t & 56;
    float m[8];
    agg_node8(node, sl, sub8, rs_deg, csr_src, Pb, m);
    if (node < N_NODES) {
        size_t off = (size_t)node * 64 + sl * 8;
        float4 q0 = *(const float4*)&H[off];
        float4 q1 = *(const float4*)&H[off + 4];
        m[0] = fmaxf(m[0] + q0.x, 0.f);
        m[1] = fmaxf(m[1] + q0.y, 0.f);
        m[2] = fmaxf(m[2] + q0.z, 0.f);
        m[3] = fmaxf(m[3] + q0.w, 0.f);
        m[4] = fmaxf(m[4] + q1.x, 0.f);
        m[5] = fmaxf(m[5] + q1.y, 0.f);
        m[6] = fmaxf(m[6] + q1.z, 0.f);
        m[7] = fmaxf(m[7] + q1.w, 0.f);
        int g = batch[node];
        int lg = g - gmin;
        if (lg < POOL_SPAN) {
#pragma unroll
            for (int j = 0; j < 8; j++)
                atomicAdd(&acc[lg * 64 + sl * 8 + j], m[j]);
        } else {
#pragma unroll
            for (int j = 0; j < 8; j++)
                atomicAdd(&psum[(size_t)g * 64 + sl * 8 + j], m[j]);
        }
    }
    __syncthreads();
    int nlast = min(nb + 31, N_NODES - 1);
    int gspan = min(batch[nlast] - gmin + 1, POOL_SPAN);
    for (int i = t; i < gspan * 64; i += 256) {
        float v = acc[i];
        if (v != 0.f)
            atomicAdd(&psum[(size_t)(gmin + (i >> 6)) * 64 + (i & 63)], v);
    }
}

// ---------------- output projection ----------------
__device__ __forceinline__ int lower_bound_batch(const int* __restrict__ batch, int val) {
    int lo = 0, hi = N_NODES;
    while (lo < hi) {
        int mid = (lo + hi) >> 1;
        if (batch[mid] < val) lo = mid + 1; else hi = mid;
    }
    return lo;
}

__global__ __launch_bounds__(256) void k_out(
    const int* __restrict__ batch, const float* __restrict__ psum,
    const float* __restrict__ Wout, const float* __restrict__ bout,
    float* __restrict__ out) {
    int w = threadIdx.x >> 6, lane = threadIdx.x & 63;
    int g = blockIdx.x * 4 + w;
    if (g >= N_GRAPHS) return;
    int s0 = lower_bound_batch(batch, g);
    int s1 = lower_bound_batch(batch, g + 1);
    int cnt = s1 - s0;
    float inv = (cnt > 0) ? 1.0f / (float)cnt : 0.0f;
    float pooled = psum[(size_t)g * 64 + lane] * inv;
#pragma unroll
    for (int c = 0; c < N_CLASSES; c++) {
        float v = pooled * Wout[lane * N_CLASSES + c];
#pragma unroll
        for (int off = 32; off > 0; off >>= 1) v += __shfl_down(v, off, 64);
        if (lane == 0) out[(size_t)g * N_CLASSES + c] = v + bout[c];
    }
}

// ---------------- launch ----------------

extern "C" void kernel_launch(void* const* d_in, const int* in_sizes, int n_in,
                              void* d_out, int out_size, void* d_ws, size_t ws_size,
                              hipStream_t stream) {
    const int*   node_ids = (const int*)d_in[0];
    const int*   edge_idx = (const int*)d_in[1];   // [2, E] row-major
    const int*   batch    = (const int*)d_in[2];
    const float* emb      = (const float*)d_in[3];
    const float* Wl0      = (const float*)d_in[4];
    const float* bl0      = (const float*)d_in[5];
    const float* Wr0      = (const float*)d_in[6];
    const float* Wl1      = (const float*)d_in[7];
    const float* bl1      = (const float*)d_in[8];
    const float* Wr1      = (const float*)d_in[9];
    const float* Wout     = (const float*)d_in[10];
    const float* bout     = (const float*)d_in[11];
    float* out = (float*)d_out;

    const int* esrc = edge_idx;
    const int* edst = edge_idx + N_EDGES;

    // workspace layout
    __hip_bfloat16* Pb0 = (__hip_bfloat16*)d_ws;              // N*64 bf16
    __hip_bfloat16* Pb1 = Pb0 + (size_t)N_NODES * 64;         // N*64 bf16
    float* H = (float*)(Pb1 + (size_t)N_NODES * 64);          // N*64 f32
    int* ebuf = (int*)(H + (size_t)N_NODES * 64);             // NB*CAP ints
    unsigned int* rs_deg = (unsigned int*)(ebuf + (size_t)NB_BKT * BKT_CAP); // N
    unsigned short* csr_src = (unsigned short*)(rs_deg + N_NODES);           // NB*CAP
    int* cnt = (int*)(csr_src + (size_t)NB_BKT * BKT_CAP);    // NB ints
    float* psum = (float*)(cnt + NB_BKT);                     // G*64 floats (contiguous w/ cnt)

    const int BLK = 256;

    // one memset zeroes bucket counters + pool accumulators (contiguous)
    hipMemsetAsync(cnt, 0, (NB_BKT + N_GRAPHS * 64) * sizeof(int), stream);

    // bucket sort (fixed-capacity regions) + per-bucket CSR
    k_bsplit<<<EB_BLOCKS, BLK, 0, stream>>>(esrc, edst, cnt, ebuf);
    k_csr_fill<<<NB_BKT, BLK, 0, stream>>>(cnt, ebuf, rs_deg, csr_src);

    // layer 0 transform (embedding gather fused)
    k_xform0<<<XFORM_BLOCKS, BLK, 0, stream>>>(node_ids, emb, Wl0, bl0, Wr0, Pb0, H);

    // fused layer-0 aggregate + layer-1 transform
    k_fused1<<<XFORM_BLOCKS, BLK, 0, stream>>>(rs_deg, csr_src, Pb0, Wl1, bl1, Wr1, Pb1, H);

    // layer-1 aggregate fused with graph pooling
    const int AGG_BLOCKS = (N_NODES * 8 + BLK - 1) / BLK;
    k_agg2_pool<<<AGG_BLOCKS, BLK, 0, stream>>>(rs_deg, csr_src, Pb1, H, batch, psum);

    // output projection
    k_out<<<(N_GRAPHS + 3) / 4, BLK, 0, stream>>>(batch, psum, Wout, bout, out);
}

// Round 11
// 222.718 us; speedup vs baseline: 3.9226x; 1.0491x over previous
//
#include <hip/hip_runtime.h>
#include <hip/hip_bf16.h>

#define N_NODES 50000
#define N_EDGES 800000
#define EMB 64
#define HID 64
#define N_CLASSES 10
#define N_GRAPHS 512

#define BKT_SHIFT 6
#define BKT_NODES 64
#define NB_BKT ((N_NODES + BKT_NODES - 1) / BKT_NODES)   // 782
#define BKT_CAP 1408     // mean 1024 + 12 sigma
#define EB_CHUNK 8192
#define EB_BLOCKS ((N_EDGES + EB_CHUNK - 1) / EB_CHUNK)  // 98
#define XFORM_BLOCKS ((N_NODES + 63) / 64)               // 782
#define XPAD 68
#define POOL_SPAN 66

// bf16 row accumulate: 8 bf16 dims (uint4) into fp32[8]
#define ACC8(vv, A)                                                            \
    do {                                                                       \
        A[0] += __uint_as_float((vv).x << 16);                                 \
        A[1] += __uint_as_float((vv).x & 0xFFFF0000u);                         \
        A[2] += __uint_as_float((vv).y << 16);                                 \
        A[3] += __uint_as_float((vv).y & 0xFFFF0000u);                         \
        A[4] += __uint_as_float((vv).z << 16);                                 \
        A[5] += __uint_as_float((vv).z & 0xFFFF0000u);                         \
        A[6] += __uint_as_float((vv).w << 16);                                 \
        A[7] += __uint_as_float((vv).w & 0xFFFF0000u);                         \
    } while (0)

// Build this bucket's CSR in LDS from its ebuf region. All 256 threads.
__device__ __forceinline__ void build_local_csr(
    int bucket, const int* __restrict__ cnt, const int* __restrict__ ebuf,
    unsigned short* lcsr, int* nhist, int* sval, int* sexcl, int* ncur) {
    int tid = threadIdx.x;
    int bs = bucket * BKT_CAP;
    int ne = min(cnt[bucket], BKT_CAP);   // defensive clamp
    if (tid < BKT_NODES) { nhist[tid] = 0; ncur[tid] = 0; }
    __syncthreads();
    for (int i = tid; i < ne; i += 256)
        atomicAdd(&nhist[ebuf[bs + i] >> 16], 1);
    __syncthreads();
    if (tid < BKT_NODES) sval[tid] = nhist[tid];
    __syncthreads();
    for (int off = 1; off < BKT_NODES; off <<= 1) {
        int t = 0;
        if (tid < BKT_NODES && tid >= off) t = nhist[tid - off];
        __syncthreads();
        if (tid < BKT_NODES) nhist[tid] += t;
        __syncthreads();
    }
    if (tid < BKT_NODES) sexcl[tid] = nhist[tid] - sval[tid];
    __syncthreads();
    for (int i = tid; i < ne; i += 256) {
        int p = ebuf[bs + i];
        int l = p >> 16;
        int r = atomicAdd(&ncur[l], 1);
        lcsr[sexcl[l] + r] = (unsigned short)(p & 0xFFFF);
    }
    __syncthreads();
}

// mean over neighbors (indices in LDS lcsr[s0..s0+deg)) for lane slot sl.
__device__ __forceinline__ void agg_node8(
    int s0, int deg, int sl,
    const unsigned short* lcsr,
    const __hip_bfloat16* __restrict__ Pb,
    float out[8]) {
    float a[4][8];
#pragma unroll
    for (int i = 0; i < 4; i++)
#pragma unroll
        for (int j = 0; j < 8; j++) a[i][j] = 0.f;
    int s1 = s0 + deg;
    for (int base = s0; base < s1; base += 8) {
        int c = min(8, s1 - base);
        if (c == 8) {
            int n0 = lcsr[base + 0];
            int n1 = lcsr[base + 1];
            int n2 = lcsr[base + 2];
            int n3 = lcsr[base + 3];
            int n4 = lcsr[base + 4];
            int n5 = lcsr[base + 5];
            int n6 = lcsr[base + 6];
            int n7 = lcsr[base + 7];
            uint4 v0 = ((const uint4*)(Pb + (size_t)n0 * 64))[sl];
            uint4 v1 = ((const uint4*)(Pb + (size_t)n1 * 64))[sl];
            uint4 v2 = ((const uint4*)(Pb + (size_t)n2 * 64))[sl];
            uint4 v3 = ((const uint4*)(Pb + (size_t)n3 * 64))[sl];
            uint4 v4 = ((const uint4*)(Pb + (size_t)n4 * 64))[sl];
            uint4 v5 = ((const uint4*)(Pb + (size_t)n5 * 64))[sl];
            uint4 v6 = ((const uint4*)(Pb + (size_t)n6 * 64))[sl];
            uint4 v7 = ((const uint4*)(Pb + (size_t)n7 * 64))[sl];
            ACC8(v0, a[0]); ACC8(v1, a[1]); ACC8(v2, a[2]); ACC8(v3, a[3]);
            ACC8(v4, a[0]); ACC8(v5, a[1]); ACC8(v6, a[2]); ACC8(v7, a[3]);
        } else {
            for (int j = 0; j < c; j++) {
                int n = lcsr[base + j];
                uint4 v = ((const uint4*)(Pb + (size_t)n * 64))[sl];
                ACC8(v, a[j & 3]);
            }
        }
    }
    float inv = (deg > 0) ? 1.0f / (float)deg : 0.0f;
#pragma unroll
    for (int j = 0; j < 8; j++)
        out[j] = (a[0][j] + a[1][j] + a[2][j] + a[3][j]) * inv;
}

// ---------------- combo: bucket multi-split (blocks 0..EB) + layer-0 xform ----------------
__global__ __launch_bounds__(256) void k_combo(
    const int* __restrict__ esrc, const int* __restrict__ edst,
    int* __restrict__ cnt, int* __restrict__ ebuf,
    const int* __restrict__ ids, const float* __restrict__ emb,
    const float* __restrict__ Wl, const float* __restrict__ bl,
    const float* __restrict__ Wr,
    __hip_bfloat16* __restrict__ Pb, float* __restrict__ Qout) {
    __shared__ float sW[64 * 64];
    __shared__ float sX[64 * XPAD];
    int t = threadIdx.x;
    if (blockIdx.x < EB_BLOCKS) {
        // ---- bsplit path: alias LDS as int scratch ----
        int* h = (int*)sW;                 // NB_BKT
        int* bbase = h + NB_BKT;           // NB_BKT
        int* cur = (int*)sX;               // NB_BKT
        for (int i = t; i < NB_BKT; i += 256) { h[i] = 0; cur[i] = 0; }
        __syncthreads();
        int base = blockIdx.x * EB_CHUNK;
        int end = min(base + EB_CHUNK, N_EDGES);
        for (int i = base + t; i < end; i += 256)
            atomicAdd(&h[edst[i] >> BKT_SHIFT], 1);
        __syncthreads();
        for (int i = t; i < NB_BKT; i += 256)
            if (h[i]) bbase[i] = i * BKT_CAP + atomicAdd(&cnt[i], h[i]);
        __syncthreads();
        for (int i = base + t; i < end; i += 256) {
            int d = edst[i], s = esrc[i];
            int b = d >> BKT_SHIFT;
            int r = atomicAdd(&cur[b], 1);
            int slot = bbase[b] + r;
            if (slot < (b + 1) * BKT_CAP)          // defensive clamp
                ebuf[slot] = ((d & (BKT_NODES - 1)) << 16) | s;
        }
        return;
    }
    // ---- xform0 path (two-pass W staging) ----
    int tile = (blockIdx.x - EB_BLOCKS) * 64;
    for (int i = t; i < 64 * 16; i += 256)
        ((float4*)sW)[i] = ((const float4*)Wl)[i];
    for (int i = t; i < 64 * 16; i += 256) {
        int r = i >> 4, c = i & 15;
        int node = tile + r;
        float4 v = make_float4(0.f, 0.f, 0.f, 0.f);
        if (node < N_NODES)
            v = ((const float4*)(emb + (size_t)ids[node] * 64))[c];
        *(float4*)&sX[r * XPAD + c * 4] = v;
    }
    __syncthreads();
    int dg = t & 15, ng = t >> 4;
    float acc[4][4];
#pragma unroll
    for (int i = 0; i < 4; i++)
#pragma unroll
        for (int j = 0; j < 4; j++) acc[i][j] = 0.f;
#pragma unroll 4
    for (int k = 0; k < 64; k++) {
        float4 w = *(const float4*)&sW[k * 64 + dg * 4];
#pragma unroll
        for (int i = 0; i < 4; i++) {
            float xv = sX[(ng + i * 16) * XPAD + k];
            acc[i][0] = fmaf(xv, w.x, acc[i][0]);
            acc[i][1] = fmaf(xv, w.y, acc[i][1]);
            acc[i][2] = fmaf(xv, w.z, acc[i][2]);
            acc[i][3] = fmaf(xv, w.w, acc[i][3]);
        }
    }
#pragma unroll
    for (int i = 0; i < 4; i++) {
        int node = tile + ng + i * 16;
        if (node < N_NODES) {
            union { ushort4 u; __hip_bfloat16 h[4]; } pk;
            pk.h[0] = __float2bfloat16(acc[i][0]);
            pk.h[1] = __float2bfloat16(acc[i][1]);
            pk.h[2] = __float2bfloat16(acc[i][2]);
            pk.h[3] = __float2bfloat16(acc[i][3]);
            *(ushort4*)&Pb[(size_t)node * 64 + dg * 4] = pk.u;
        }
    }
    __syncthreads();
    for (int i = t; i < 64 * 16; i += 256)
        ((float4*)sW)[i] = ((const float4*)Wr)[i];
    __syncthreads();
#pragma unroll
    for (int i = 0; i < 4; i++)
#pragma unroll
        for (int j = 0; j < 4; j++) acc[i][j] = 0.f;
#pragma unroll 4
    for (int k = 0; k < 64; k++) {
        float4 w = *(const float4*)&sW[k * 64 + dg * 4];
#pragma unroll
        for (int i = 0; i < 4; i++) {
            float xv = sX[(ng + i * 16) * XPAD + k];
            acc[i][0] = fmaf(xv, w.x, acc[i][0]);
            acc[i][1] = fmaf(xv, w.y, acc[i][1]);
            acc[i][2] = fmaf(xv, w.z, acc[i][2]);
            acc[i][3] = fmaf(xv, w.w, acc[i][3]);
        }
    }
    float4 blv = *(const float4*)&bl[dg * 4];
#pragma unroll
    for (int i = 0; i < 4; i++) {
        int node = tile + ng + i * 16;
        if (node < N_NODES)
            *(float4*)&Qout[(size_t)node * 64 + dg * 4] =
                make_float4(acc[i][0] + blv.x, acc[i][1] + blv.y,
                            acc[i][2] + blv.z, acc[i][3] + blv.w);
    }
}

// ---------------- fused: LDS CSR + layer-0 aggregate + layer-1 xform ----------------
// Block = bucket = 64-node tile. H0 built in LDS, then two-pass GEMM.
__global__ __launch_bounds__(256) void k_fused1(
    const int* __restrict__ cnt, const int* __restrict__ ebuf,
    const __hip_bfloat16* __restrict__ Pb0, const float* __restrict__ Wl,
    const float* __restrict__ bl, const float* __restrict__ Wr,
    __hip_bfloat16* __restrict__ Pb1, float* __restrict__ H) {
    __shared__ float sW[64 * 64];
    __shared__ float sX[64 * XPAD];
    __shared__ unsigned short lcsr[BKT_CAP];
    __shared__ int nhist[BKT_NODES], sval[BKT_NODES], sexcl[BKT_NODES], ncur[BKT_NODES];
    int t = threadIdx.x;
    int tile = blockIdx.x * 64;
    // Wl prefetch issues early; hides behind CSR build + gather
    for (int i = t; i < 64 * 16; i += 256)
        ((float4*)sW)[i] = ((const float4*)Wl)[i];
    build_local_csr(blockIdx.x, cnt, ebuf, lcsr, nhist, sval, sexcl, ncur);
    // phase (a): aggregate 2 nodes per eighth-wave, H0 = relu(mean+Q0) -> sX
    int grp = t >> 3, sl = t & 7;
    for (int nn = 0; nn < 2; nn++) {
        int ln = grp * 2 + nn;
        int node = tile + ln;
        float m[8];
        agg_node8(sexcl[ln], sval[ln], sl, lcsr, Pb0, m);
        if (node < N_NODES) {
            size_t off = (size_t)node * 64 + sl * 8;
            float4 q0 = *(const float4*)&H[off];
            float4 q1 = *(const float4*)&H[off + 4];
            m[0] = fmaxf(m[0] + q0.x, 0.f);
            m[1] = fmaxf(m[1] + q0.y, 0.f);
            m[2] = fmaxf(m[2] + q0.z, 0.f);
            m[3] = fmaxf(m[3] + q0.w, 0.f);
            m[4] = fmaxf(m[4] + q1.x, 0.f);
            m[5] = fmaxf(m[5] + q1.y, 0.f);
            m[6] = fmaxf(m[6] + q1.z, 0.f);
            m[7] = fmaxf(m[7] + q1.w, 0.f);
        } else {
#pragma unroll
            for (int j = 0; j < 8; j++) m[j] = 0.f;
        }
        *(float4*)&sX[ln * XPAD + sl * 8] = make_float4(m[0], m[1], m[2], m[3]);
        *(float4*)&sX[ln * XPAD + sl * 8 + 4] = make_float4(m[4], m[5], m[6], m[7]);
    }
    __syncthreads();
    // phase (b1): Pb1 = H0 @ Wl
    int dg = t & 15, ng = t >> 4;
    float acc[4][4];
#pragma unroll
    for (int i = 0; i < 4; i++)
#pragma unroll
        for (int j = 0; j < 4; j++) acc[i][j] = 0.f;
#pragma unroll 4
    for (int k = 0; k < 64; k++) {
        float4 w = *(const float4*)&sW[k * 64 + dg * 4];
#pragma unroll
        for (int i = 0; i < 4; i++) {
            float xv = sX[(ng + i * 16) * XPAD + k];
            acc[i][0] = fmaf(xv, w.x, acc[i][0]);
            acc[i][1] = fmaf(xv, w.y, acc[i][1]);
            acc[i][2] = fmaf(xv, w.z, acc[i][2]);
            acc[i][3] = fmaf(xv, w.w, acc[i][3]);
        }
    }
#pragma unroll
    for (int i = 0; i < 4; i++) {
        int node = tile + ng + i * 16;
        if (node < N_NODES) {
            union { ushort4 u; __hip_bfloat16 h[4]; } pk;
            pk.h[0] = __float2bfloat16(acc[i][0]);
            pk.h[1] = __float2bfloat16(acc[i][1]);
            pk.h[2] = __float2bfloat16(acc[i][2]);
            pk.h[3] = __float2bfloat16(acc[i][3]);
            *(ushort4*)&Pb1[(size_t)node * 64 + dg * 4] = pk.u;
        }
    }
    __syncthreads();
    for (int i = t; i < 64 * 16; i += 256)
        ((float4*)sW)[i] = ((const float4*)Wr)[i];
    __syncthreads();
    // phase (b2): H = Q1 = H0 @ Wr + bl
#pragma unroll
    for (int i = 0; i < 4; i++)
#pragma unroll
        for (int j = 0; j < 4; j++) acc[i][j] = 0.f;
#pragma unroll 4
    for (int k = 0; k < 64; k++) {
        float4 w = *(const float4*)&sW[k * 64 + dg * 4];
#pragma unroll
        for (int i = 0; i < 4; i++) {
            float xv = sX[(ng + i * 16) * XPAD + k];
            acc[i][0] = fmaf(xv, w.x, acc[i][0]);
            acc[i][1] = fmaf(xv, w.y, acc[i][1]);
            acc[i][2] = fmaf(xv, w.z, acc[i][2]);
            acc[i][3] = fmaf(xv, w.w, acc[i][3]);
        }
    }
    float4 blv = *(const float4*)&bl[dg * 4];
#pragma unroll
    for (int i = 0; i < 4; i++) {
        int node = tile + ng + i * 16;
        if (node < N_NODES)
            *(float4*)&H[(size_t)node * 64 + dg * 4] =
                make_float4(acc[i][0] + blv.x, acc[i][1] + blv.y,
                            acc[i][2] + blv.z, acc[i][3] + blv.w);
    }
}

// ---------------- layer-1 aggregate + pooling (block = bucket = 64 nodes) ----------------
__global__ __launch_bounds__(256) void k_agg2_pool(
    const int* __restrict__ cnt, const int* __restrict__ ebuf,
    const __hip_bfloat16* __restrict__ Pb, const float* __restrict__ H,
    const int* __restrict__ batch, float* __restrict__ psum) {
    __shared__ float acc[POOL_SPAN * 64];
    __shared__ unsigned short lcsr[BKT_CAP];
    __shared__ int nhist[BKT_NODES], sval[BKT_NODES], sexcl[BKT_NODES], ncur[BKT_NODES];
    int t = threadIdx.x;
    int nb = blockIdx.x * 64;
    for (int i = t; i < POOL_SPAN * 64; i += 256) acc[i] = 0.f;
    build_local_csr(blockIdx.x, cnt, ebuf, lcsr, nhist, sval, sexcl, ncur);
    int gmin = batch[nb];
    int grp = t >> 3, sl = t & 7;
    for (int nn = 0; nn < 2; nn++) {
        int ln = grp * 2 + nn;
        int node = nb + ln;
        float m[8];
        agg_node8(sexcl[ln], sval[ln], sl, lcsr, Pb, m);
        if (node < N_NODES) {
            size_t off = (size_t)node * 64 + sl * 8;
            float4 q0 = *(const float4*)&H[off];
            float4 q1 = *(const float4*)&H[off + 4];
            m[0] = fmaxf(m[0] + q0.x, 0.f);
            m[1] = fmaxf(m[1] + q0.y, 0.f);
            m[2] = fmaxf(m[2] + q0.z, 0.f);
            m[3] = fmaxf(m[3] + q0.w, 0.f);
            m[4] = fmaxf(m[4] + q1.x, 0.f);
            m[5] = fmaxf(m[5] + q1.y, 0.f);
            m[6] = fmaxf(m[6] + q1.z, 0.f);
            m[7] = fmaxf(m[7] + q1.w, 0.f);
            int g = batch[node];
            int lg = g - gmin;
            if (lg < POOL_SPAN) {
#pragma unroll
                for (int j = 0; j < 8; j++)
                    atomicAdd(&acc[lg * 64 + sl * 8 + j], m[j]);
            } else {
#pragma unroll
                for (int j = 0; j < 8; j++)
                    atomicAdd(&psum[(size_t)g * 64 + sl * 8 + j], m[j]);
            }
        }
    }
    __syncthreads();
    int nlast = min(nb + 63, N_NODES - 1);
    int gspan = min(batch[nlast] - gmin + 1, POOL_SPAN);
    for (int i = t; i < gspan * 64; i += 256) {
        float v = acc[i];
        if (v != 0.f)
            atomicAdd(&psum[(size_t)(gmin + (i >> 6)) * 64 + (i & 63)], v);
    }
}

// ---------------- output projection ----------------
__device__ __forceinline__ int lower_bound_batch(const int* __restrict__ batch, int val) {
    int lo = 0, hi = N_NODES;
    while (lo < hi) {
        int mid = (lo + hi) >> 1;
        if (batch[mid] < val) lo = mid + 1; else hi = mid;
    }
    return lo;
}

__global__ __launch_bounds__(256) void k_out(
    const int* __restrict__ batch, const float* __restrict__ psum,
    const float* __restrict__ Wout, const float* __restrict__ bout,
    float* __restrict__ out) {
    int w = threadIdx.x >> 6, lane = threadIdx.x & 63;
    int g = blockIdx.x * 4 + w;
    if (g >= N_GRAPHS) return;
    int s0 = lower_bound_batch(batch, g);
    int s1 = lower_bound_batch(batch, g + 1);
    int cntg = s1 - s0;
    float inv = (cntg > 0) ? 1.0f / (float)cntg : 0.0f;
    float pooled = psum[(size_t)g * 64 + lane] * inv;
#pragma unroll
    for (int c = 0; c < N_CLASSES; c++) {
        float v = pooled * Wout[lane * N_CLASSES + c];
#pragma unroll
        for (int off = 32; off > 0; off >>= 1) v += __shfl_down(v, off, 64);
        if (lane == 0) out[(size_t)g * N_CLASSES + c] = v + bout[c];
    }
}

// ---------------- launch ----------------

extern "C" void kernel_launch(void* const* d_in, const int* in_sizes, int n_in,
                              void* d_out, int out_size, void* d_ws, size_t ws_size,
                              hipStream_t stream) {
    const int*   node_ids = (const int*)d_in[0];
    const int*   edge_idx = (const int*)d_in[1];   // [2, E] row-major
    const int*   batch    = (const int*)d_in[2];
    const float* emb      = (const float*)d_in[3];
    const float* Wl0      = (const float*)d_in[4];
    const float* bl0      = (const float*)d_in[5];
    const float* Wr0      = (const float*)d_in[6];
    const float* Wl1      = (const float*)d_in[7];
    const float* bl1      = (const float*)d_in[8];
    const float* Wr1      = (const float*)d_in[9];
    const float* Wout     = (const float*)d_in[10];
    const float* bout     = (const float*)d_in[11];
    float* out = (float*)d_out;

    const int* esrc = edge_idx;
    const int* edst = edge_idx + N_EDGES;

    // workspace layout
    __hip_bfloat16* Pb0 = (__hip_bfloat16*)d_ws;              // N*64 bf16
    __hip_bfloat16* Pb1 = Pb0 + (size_t)N_NODES * 64;         // N*64 bf16
    float* H = (float*)(Pb1 + (size_t)N_NODES * 64);          // N*64 f32
    int* ebuf = (int*)(H + (size_t)N_NODES * 64);             // NB*CAP ints
    int* cnt = ebuf + (size_t)NB_BKT * BKT_CAP;               // NB ints
    float* psum = (float*)(cnt + NB_BKT);                     // G*64 floats (contiguous w/ cnt)

    const int BLK = 256;

    // one memset zeroes bucket counters + pool accumulators (contiguous)
    hipMemsetAsync(cnt, 0, (NB_BKT + N_GRAPHS * 64) * sizeof(int), stream);

    // combo: bucket multi-split (98 blocks) + layer-0 xform (782 blocks)
    k_combo<<<EB_BLOCKS + XFORM_BLOCKS, BLK, 0, stream>>>(
        esrc, edst, cnt, ebuf, node_ids, emb, Wl0, bl0, Wr0, Pb0, H);

    // fused layer-0 aggregate (LDS CSR) + layer-1 transform
    k_fused1<<<XFORM_BLOCKS, BLK, 0, stream>>>(cnt, ebuf, Pb0, Wl1, bl1, Wr1, Pb1, H);

    // layer-1 aggregate (LDS CSR) fused with graph pooling
    k_agg2_pool<<<NB_BKT, BLK, 0, stream>>>(cnt, ebuf, Pb1, H, batch, psum);

    // output projection
    k_out<<<(N_GRAPHS + 3) / 4, BLK, 0, stream>>>(batch, psum, Wout, bout, out);
}